// Round 4
// baseline (619.214 us; speedup 1.0000x reference)
//
#include <hip/hip_runtime.h>
#include <stdint.h>

#define B_ 1024
#define Q_ 65536
#define D_ 512
#define MT 128
#define NT 128
#define BK 64
#define NSPLIT 64
#define NCHUNK (Q_ / NSPLIT)   // 1024
#define NTILES (NCHUNK / NT)   // 8
#define KITERS (D_ / BK)       // 8

#define SCALE32 32.0f
#define C32 46.16624130844683f   // 32 * log2(e)

// ---- workspace layout (bytes) ----
// [0,8K)   : rowv[2][B] f32 per-row loss values
// [16K)    : LSE partials float2(Z_mat0, Z_mat1), idx row*64+split  (512 KB)
// [1 MB)   : top-10 partials, idx ((mat*B+row)*64+split)*10         (5.24 MB)
// [8 MB)   : p bf16 (1 MB)
// [12 MB)  : queue[0] bf16 (64 MB)
// [76 MB)  : w = m*q1+(1-m)*q0 bf16, written only where mask!=0 (64 MB region)
#define WS_ROWV 0
#define WS_LSE  16384
#define WS_TOPK (1u * 1024u * 1024u)
#define WS_PBF  (8u * 1024u * 1024u)
#define WS_QBF0 (12u * 1024u * 1024u)
#define WS_WBF  (76u * 1024u * 1024u)

// ---- LDS: single staging buffer SA[0,16K) SB0[16K,32K) SB1[32K,48K),
// 16B-XOR swizzle (sc16 = (lane&7)^srow, proven round-0: 2.9M conflicts).
// topk compact (16 KB) aliases SA between the K-loop's trailing barrier and
// the next nt's staging.
#define SA_OFF 0
#define SB0_OFF 16384
#define SB1_OFF 32768

typedef __attribute__((ext_vector_type(8))) short short8;
typedef __attribute__((ext_vector_type(4))) short short4v;
typedef __attribute__((ext_vector_type(4))) float f32x4;

__device__ __forceinline__ unsigned short f2bf(float x) {
  union { float f; uint32_t u; } v; v.f = x;
  uint32_t r = v.u + 0x7fffu + ((v.u >> 16) & 1u);   // RNE
  return (unsigned short)(r >> 16);
}

__device__ __forceinline__ float bf2f(short u) {
  union { uint32_t i; float f; } v;
  v.i = ((uint32_t)(unsigned short)u) << 16;
  return v.f;
}

__device__ __forceinline__ void async16(void* lds, const void* g) {
  void* gg = (void*)g;
  __builtin_amdgcn_global_load_lds(
      (__attribute__((address_space(1))) unsigned int*)gg,
      (__attribute__((address_space(3))) unsigned int*)lds,
      16, 0, 0);
}

__device__ __forceinline__ void tkins(float v,
    float& t0, float& t1, float& t2, float& t3, float& t4,
    float& t5, float& t6, float& t7, float& t8, float& t9) {
  if (v > t9) {
    t9 = (v > t8) ? t8 : v;
    t8 = (v > t8) ? ((v > t7) ? t7 : v) : t8;
    t7 = (v > t7) ? ((v > t6) ? t6 : v) : t7;
    t6 = (v > t6) ? ((v > t5) ? t5 : v) : t6;
    t5 = (v > t5) ? ((v > t4) ? t4 : v) : t5;
    t4 = (v > t4) ? ((v > t3) ? t3 : v) : t4;
    t3 = (v > t3) ? ((v > t2) ? t2 : v) : t3;
    t2 = (v > t2) ? ((v > t1) ? t1 : v) : t2;
    t1 = (v > t1) ? ((v > t0) ? t0 : v) : t1;
    t0 = (v > t0) ? v : t0;
  }
}

#define TKA(v, a) tkins((v), a[0], a[1], a[2], a[3], a[4], a[5], a[6], a[7], a[8], a[9])

// fused converter: queue fp32 -> qbf0 always; wbf only where mask!=0; p -> pbf
__global__ void cvt_all(const float* __restrict__ q, const float* __restrict__ p,
                        const float* __restrict__ mask,
                        unsigned short* __restrict__ qbf0,
                        unsigned short* __restrict__ wbf,
                        unsigned short* __restrict__ pbf) {
  const int wv = threadIdx.x >> 6;
  const int lane = threadIdx.x & 63;
  const int b = blockIdx.x;
  if (b < Q_ / 4) {
    const int row = b * 4 + wv;
    const float* q0r = q + (size_t)row * D_ + lane * 8;
    float4 a = ((const float4*)q0r)[0];
    float4 bb = ((const float4*)q0r)[1];
    short8 o;
    o[0] = (short)f2bf(a.x); o[1] = (short)f2bf(a.y);
    o[2] = (short)f2bf(a.z); o[3] = (short)f2bf(a.w);
    o[4] = (short)f2bf(bb.x); o[5] = (short)f2bf(bb.y);
    o[6] = (short)f2bf(bb.z); o[7] = (short)f2bf(bb.w);
    *(short8*)(qbf0 + (size_t)row * D_ + lane * 8) = o;
    float m = mask[row];
    if (m != 0.0f) {      // wave-uniform; ~10% of rows
      const float* q1r = q0r + (size_t)Q_ * D_;
      float4 c = ((const float4*)q1r)[0];
      float4 d = ((const float4*)q1r)[1];
      a.x = fmaf(m, c.x - a.x, a.x); a.y = fmaf(m, c.y - a.y, a.y);
      a.z = fmaf(m, c.z - a.z, a.z); a.w = fmaf(m, c.w - a.w, a.w);
      bb.x = fmaf(m, d.x - bb.x, bb.x); bb.y = fmaf(m, d.y - bb.y, bb.y);
      bb.z = fmaf(m, d.z - bb.z, bb.z); bb.w = fmaf(m, d.w - bb.w, bb.w);
      o[0] = (short)f2bf(a.x); o[1] = (short)f2bf(a.y);
      o[2] = (short)f2bf(a.z); o[3] = (short)f2bf(a.w);
      o[4] = (short)f2bf(bb.x); o[5] = (short)f2bf(bb.y);
      o[6] = (short)f2bf(bb.z); o[7] = (short)f2bf(bb.w);
      *(short8*)(wbf + (size_t)row * D_ + lane * 8) = o;
    }
  } else {
    const int row = (b - Q_ / 4) * 4 + wv;
    const float* pr = p + (size_t)row * D_ + lane * 8;
    float4 a = ((const float4*)pr)[0];
    float4 bb = ((const float4*)pr)[1];
    short8 o;
    o[0] = (short)f2bf(a.x); o[1] = (short)f2bf(a.y);
    o[2] = (short)f2bf(a.z); o[3] = (short)f2bf(a.w);
    o[4] = (short)f2bf(bb.x); o[5] = (short)f2bf(bb.y);
    o[6] = (short)f2bf(bb.z); o[7] = (short)f2bf(bb.w);
    *(short8*)(pbf + (size_t)row * D_ + lane * 8) = o;
  }
}

// grid (64, 8): x=split -> XCD=split%8, all 512 blocks co-resident (2/CU).
// 512 threads = 8 waves (2M x 4N) on the 128x128 tile -> 16 waves/CU (4/SIMD)
// to densify latency hiding across the two co-resident blocks. K-loop is the
// proven round-0 single-buffer 2-barrier form (BK=64 staging + swizzle exact).
__global__ __launch_bounds__(512, 4) void fused_gemm_partial(
    const unsigned short* __restrict__ pbf,
    const unsigned short* __restrict__ qbf0,
    const unsigned short* __restrict__ wbf,
    const float* __restrict__ maskp,
    const int* __restrict__ label,
    char* __restrict__ ws) {
  __shared__ __align__(16) unsigned char smem[49152];
  __shared__ float maskb[NT];
  __shared__ float zacc[MT][8];      // [row][wc*2+mat], accumulated across nt
  __shared__ int olist[MT];
  __shared__ int rowmap[MT];
  __shared__ int sh_ocount;

  const int tid = threadIdx.x;
  const int split = blockIdx.x;       // 0..63
  const int mblk = blockIdx.y;        // 0..7
  const int lane = tid & 63;
  const int wv = tid >> 6;            // 0..7
  const int wr = wv >> 2;             // 0..1 : 64-row band
  const int wc = wv & 3;              // 0..3 : 32-col band
  const int lr = lane & 15;
  const int lg = lane >> 4;

  if (tid == 0) sh_ocount = 0;
  if (tid < MT) {
    rowmap[tid] = -1;
#pragma unroll
    for (int c = 0; c < 8; ++c) zacc[tid][c] = 0.0f;
  }
  __syncthreads();
  if (tid < MT) {
    if (label[mblk * MT + tid] == -1) {
      int k = atomicAdd(&sh_ocount, 1);
      olist[k] = tid;
    }
  }
  __syncthreads();
  const int noc = sh_ocount;
  if (tid < noc) rowmap[olist[tid]] = tid;
  __syncthreads();
  const int nchunks = (noc + 31) >> 5;

  // staging lane constants (round-0 exact): lane covers row slot*8+(lane>>3),
  // swizzled col16 = (lane&7) ^ (row&7)
  const int srow = lane >> 3;
  const int sc16 = (lane & 7) ^ srow;
  const size_t g_lane_off = (size_t)srow * D_ + sc16 * 8;

  // owner top-10 (only threads with tid&3==0 and pair<64 use it)
  float T[10];
#pragma unroll
  for (int i = 0; i < 10; ++i) T[i] = -1e30f;

  for (int nt = 0; nt < NTILES; ++nt) {
    const int nbase = split * NCHUNK + nt * NT;
    if (tid < NT) maskb[tid] = maskp[nbase + tid];
    __syncthreads();   // maskb ready; also fences smem reuse from prev nt scan

    // per-slot B1 source select (mask==0 rows read qbf0 -> L2-hot after B0)
    const unsigned short* b1b[2];
#pragma unroll
    for (int t = 0; t < 2; ++t) {
      const int rowl = (wv * 2 + t) * 8 + srow;
      b1b[t] = (maskb[rowl] != 0.0f) ? wbf : qbf0;
    }

    f32x4 acc0[4][2], acc1[4][2];
#pragma unroll
    for (int i = 0; i < 4; ++i)
#pragma unroll
      for (int j = 0; j < 2; ++j) {
        f32x4 z = {0.0f, 0.0f, 0.0f, 0.0f};
        acc0[i][j] = z;
        acc1[i][j] = z;
      }

    for (int kk = 0; kk < KITERS; ++kk) {
      const size_t kcol = (size_t)kk * BK;
#pragma unroll
      for (int t = 0; t < 2; ++t) {
        const int slot = wv * 2 + t;
        const size_t rbase = (size_t)slot * 8;
        async16(smem + SA_OFF + slot * 1024,
                pbf + ((size_t)mblk * MT + rbase) * D_ + kcol + g_lane_off);
        async16(smem + SB0_OFF + slot * 1024,
                qbf0 + ((size_t)nbase + rbase) * D_ + kcol + g_lane_off);
        async16(smem + SB1_OFF + slot * 1024,
                b1b[t] + ((size_t)nbase + rbase) * D_ + kcol + g_lane_off);
      }
      __syncthreads();

#pragma unroll
      for (int s = 0; s < 2; ++s) {
        const int xs = ((s * 4 + lg) ^ (lr & 7)) * 16;
        short8 af[4], bf0[2], bf1[2];
#pragma unroll
        for (int i = 0; i < 4; ++i)
          af[i] = *(const short8*)(smem + SA_OFF + (wr * 64 + i * 16 + lr) * 128 + xs);
#pragma unroll
        for (int j = 0; j < 2; ++j)
          bf0[j] = *(const short8*)(smem + SB0_OFF + (wc * 32 + j * 16 + lr) * 128 + xs);
#pragma unroll
        for (int j = 0; j < 2; ++j)
          bf1[j] = *(const short8*)(smem + SB1_OFF + (wc * 32 + j * 16 + lr) * 128 + xs);
#pragma unroll
        for (int i = 0; i < 4; ++i)
#pragma unroll
          for (int j = 0; j < 2; ++j)
            acc0[i][j] = __builtin_amdgcn_mfma_f32_16x16x32_bf16(af[i], bf0[j], acc0[i][j], 0, 0, 0);
#pragma unroll
        for (int i = 0; i < 4; ++i)
#pragma unroll
          for (int j = 0; j < 2; ++j)
            acc1[i][j] = __builtin_amdgcn_mfma_f32_16x16x32_bf16(af[i], bf1[j], acc1[i][j], 0, 0, 0);
      }
      __syncthreads();
    }

    // ---- Z epilogue: exps in regs, lr-shuffle reduce, LDS accumulate ----
#pragma unroll
    for (int i = 0; i < 4; ++i)
#pragma unroll
      for (int k = 0; k < 4; ++k) {
        float a0 = 0.0f, a1 = 0.0f;
#pragma unroll
        for (int j = 0; j < 2; ++j) {
          a0 += __builtin_amdgcn_exp2f(fmaf(acc0[i][j][k], C32, -C32));
          a1 += __builtin_amdgcn_exp2f(fmaf(acc1[i][j][k], C32, -C32));
        }
#pragma unroll
        for (int m = 1; m < 16; m <<= 1) {
          a0 += __shfl_xor(a0, m, 64);
          a1 += __shfl_xor(a1, m, 64);
        }
        if (lr == 0) {
          const int r = wr * 64 + i * 16 + lg * 4 + k;
          zacc[r][wc * 2 + 0] += a0;
          zacc[r][wc * 2 + 1] += a1;
        }
      }

    // ---- top-10 for outlier rows: LDS compact -> 4-thread scans -> merge ----
    for (int c = 0; c < nchunks; ++c) {
      unsigned short* cp = (unsigned short*)smem;   // aliases SA (16 KB)
#pragma unroll
      for (int i = 0; i < 4; ++i)
#pragma unroll
        for (int k = 0; k < 4; ++k) {
          const int r = wr * 64 + i * 16 + lg * 4 + k;
          const int o = rowmap[r];
          const int ol = o - c * 32;
          if (o >= 0 && ol >= 0 && ol < 32) {
#pragma unroll
            for (int j = 0; j < 2; ++j) {
              const int col = wc * 32 + j * 16 + lr;
              cp[ol * 128 + col] = f2bf(acc0[i][j][k]);
              cp[(32 + ol) * 128 + col] = f2bf(acc1[i][j][k]);
            }
          }
        }
      __syncthreads();

      {
        float tl[10];
#pragma unroll
        for (int r = 0; r < 10; ++r) tl[r] = -1e30f;
        const int pair = tid >> 2;      // 0..127: (orow, mat); only pair<64 active
        const int q4 = tid & 3;
        const int orow = pair >> 1, mat = pair & 1;
        const int o = c * 32 + orow;
        if (orow < 32 && o < noc) {
          const unsigned short* rp = cp + (mat * 32 + orow) * 128 + q4 * 32;
#pragma unroll
          for (int cc = 0; cc < 8; ++cc) {
            short4v v = *(const short4v*)(rp + cc * 4);
            TKA(bf2f(v.x), tl); TKA(bf2f(v.y), tl);
            TKA(bf2f(v.z), tl); TKA(bf2f(v.w), tl);
          }
          // merge across the 4 quarter-threads (same wave: xor 1 then 2)
          float ot[10];
#pragma unroll
          for (int r = 0; r < 10; ++r) ot[r] = __shfl_xor(tl[r], 1, 64);
#pragma unroll
          for (int r = 0; r < 10; ++r) TKA(ot[r], tl);
#pragma unroll
          for (int r = 0; r < 10; ++r) ot[r] = __shfl_xor(tl[r], 2, 64);
#pragma unroll
          for (int r = 0; r < 10; ++r) TKA(ot[r], tl);
          if (q4 == 0) {
            if (c == 0) {
#pragma unroll
              for (int r = 0; r < 10; ++r) TKA(tl[r], T);
            } else {
              // rare overflow path (noc > 32): RMW ws slot per nt
              float* slot = (float*)(ws + WS_TOPK) +
                  ((size_t)(mat * B_ + mblk * MT + olist[o]) * NSPLIT + split) * 10;
              if (nt == 0) {
#pragma unroll
                for (int r = 0; r < 10; ++r) slot[r] = tl[r];
              } else {
                float cur[10];
#pragma unroll
                for (int r = 0; r < 10; ++r) cur[r] = slot[r];
#pragma unroll
                for (int r = 0; r < 10; ++r) TKA(tl[r], cur);
#pragma unroll
                for (int r = 0; r < 10; ++r) slot[r] = cur[r];
              }
            }
          }
        }
      }
      __syncthreads();
    }
  }

  __syncthreads();
  // ---- block end: write Z partials and owner top-10 lists ----
  if (tid < MT) {
    float2* lseo = (float2*)(ws + WS_LSE);
    lseo[(size_t)(mblk * MT + tid) * NSPLIT + split] = make_float2(
        zacc[tid][0] + zacc[tid][2] + zacc[tid][4] + zacc[tid][6],
        zacc[tid][1] + zacc[tid][3] + zacc[tid][5] + zacc[tid][7]);
  }
  {
    const int pair = tid >> 2;
    const int q4 = tid & 3;
    const int orow = pair >> 1, mat = pair & 1;
    if (q4 == 0 && orow < noc && orow < 32) {
      float* slot = (float*)(ws + WS_TOPK) +
          ((size_t)(mat * B_ + mblk * MT + olist[orow]) * NSPLIT + split) * 10;
#pragma unroll
      for (int r = 0; r < 10; ++r) slot[r] = T[r];
    }
  }
}

// per-row: no global atomics — each row writes rowv[l*B+row]; reduce_final sums.
__global__ void finalize_rows(
    const float* __restrict__ p, const float* __restrict__ queue,
    const float* __restrict__ maskp, const int* __restrict__ label,
    char* __restrict__ ws, float* __restrict__ out) {
  const int row = blockIdx.x;
  const int l = threadIdx.x >> 6;     // 0: cos1 loss, 1: cos2 loss
  const int lane = threadIdx.x & 63;
  const int lab = label[row];
  float* rowv = (float*)(ws + WS_ROWV);

  if (lab != -1) {
    // ---- sum 64 split Z partials ----
    const float2* lsep = (const float2*)(ws + WS_LSE) + (size_t)row * NSPLIT;
    float2 zz = lsep[lane];
    float z = (l == 0) ? zz.x : zz.y;
#pragma unroll
    for (int o = 1; o < 64; o <<= 1) z += __shfl_xor(z, o, 64);

    // ---- exact fp32 gt dot(s) ----
    const float* prow = p + (size_t)row * D_;
    const float* q0r = queue + (size_t)lab * D_;
    const float* q1r = queue + ((size_t)Q_ + (size_t)lab) * D_;
    int c = lane * 8;
    float4 a0 = *(const float4*)(prow + c);
    float4 a1 = *(const float4*)(prow + c + 4);
    float4 b0 = *(const float4*)(q0r + c);
    float4 b1 = *(const float4*)(q0r + c + 4);
    float d0 = a0.x * b0.x + a0.y * b0.y + a0.z * b0.z + a0.w * b0.w
             + a1.x * b1.x + a1.y * b1.y + a1.z * b1.z + a1.w * b1.w;
    float d1 = 0.0f;
    if (l == 1) {
      float4 c0 = *(const float4*)(q1r + c);
      float4 c1 = *(const float4*)(q1r + c + 4);
      d1 = a0.x * c0.x + a0.y * c0.y + a0.z * c0.z + a0.w * c0.w
         + a1.x * c1.x + a1.y * c1.y + a1.z * c1.z + a1.w * c1.w;
    }
#pragma unroll
    for (int o = 1; o < 64; o <<= 1) {
      d0 += __shfl_xor(d0, o, 64);
      d1 += __shfl_xor(d1, o, 64);
    }
    float gt;
    if (l == 0) gt = d0;
    else { float m = maskp[lab]; gt = fmaf(m, d1 - d0, d0); }

    if (lane == 0) {
      float e1 = __builtin_amdgcn_exp2f(fmaf(gt, C32, -C32));
      float e2 = __builtin_amdgcn_exp2f(fmaf(gt - 0.4f, C32, -C32));
      float Zc = z - e1 + e2;
      float ce = 32.0f + __logf(Zc) - (gt - 0.4f) * SCALE32;
      rowv[l * B_ + row] = ce;
    }
  } else {
    // ---- merge 64 sorted top-10 lists: 10-round wave tournament ----
    const float* tp = (const float*)(ws + WS_TOPK) +
                      ((size_t)l * B_ + row) * NSPLIT * 10 + (size_t)lane * 10;
    float t0 = tp[0], t1 = tp[1], t2 = tp[2], t3 = tp[3], t4 = tp[4];
    float t5 = tp[5], t6 = tp[6], t7 = tp[7], t8 = tp[8], t9 = tp[9];
    float ssum = 0.0f;
#pragma unroll
    for (int r10 = 0; r10 < 10; ++r10) {
      float v = t0;
      int idx = lane;
#pragma unroll
      for (int o = 1; o < 64; o <<= 1) {
        float ov = __shfl_xor(v, o, 64);
        int oi = __shfl_xor(idx, o, 64);
        bool take = (ov > v) || (ov == v && oi < idx);
        v = take ? ov : v;
        idx = take ? oi : idx;
      }
      ssum += fmaxf(v, 0.0f);
      if (idx == lane) {
        t0 = t1; t1 = t2; t2 = t3; t3 = t4; t4 = t5;
        t5 = t6; t6 = t7; t7 = t8; t8 = t9; t9 = -1e30f;
      }
    }
    if (lane == 0) rowv[l * B_ + row] = ssum * 0.1f;
  }
}

// single-block deterministic reduction (no contended atomics)
__global__ void reduce_final(const int* __restrict__ label,
                             const char* __restrict__ ws,
                             float* __restrict__ out) {
  __shared__ float sce[4], sng[4];
  __shared__ int snp[4], snn[4];
  const int tid = threadIdx.x;        // 256 threads
  const float* rowv = (const float*)(ws + WS_ROWV);
  float ce = 0.0f, ng = 0.0f;
  int np = 0, nn = 0;
  for (int r = tid; r < B_; r += 256) {
    float v = rowv[r] + rowv[B_ + r];
    if (label[r] != -1) { ce += v; ++np; }
    else { ng += v; ++nn; }
  }
#pragma unroll
  for (int o = 1; o < 64; o <<= 1) {
    ce += __shfl_xor(ce, o, 64);
    ng += __shfl_xor(ng, o, 64);
    np += __shfl_xor(np, o, 64);
    nn += __shfl_xor(nn, o, 64);
  }
  const int wv = tid >> 6, lane = tid & 63;
  if (lane == 0) { sce[wv] = ce; sng[wv] = ng; snp[wv] = np; snn[wv] = nn; }
  __syncthreads();
  if (tid == 0) {
    float c = 0.0f, g = 0.0f; int p = 0, n = 0;
#pragma unroll
    for (int i = 0; i < 4; ++i) { c += sce[i]; g += sng[i]; p += snp[i]; n += snn[i]; }
    float loss = 0.0f;
    if (p > 0) loss += c / (float)p;
    if (n > 0) loss += g / (float)n;
    out[0] = loss;
  }
}

extern "C" void kernel_launch(void* const* d_in, const int* in_sizes, int n_in,
                              void* d_out, int out_size, void* d_ws, size_t ws_size,
                              hipStream_t stream) {
  const float* p     = (const float*)d_in[0];
  const float* queue = (const float*)d_in[1];
  const float* maskp = (const float*)d_in[2];
  const int*   label = (const int*)d_in[3];
  float* out = (float*)d_out;
  char* ws = (char*)d_ws;

  unsigned short* pbf  = (unsigned short*)(ws + WS_PBF);
  unsigned short* qbf0 = (unsigned short*)(ws + WS_QBF0);
  unsigned short* wbf  = (unsigned short*)(ws + WS_WBF);

  cvt_all<<<Q_ / 4 + B_ / 4, 256, 0, stream>>>(queue, p, maskp, qbf0, wbf, pbf);

  dim3 g1(NSPLIT, B_ / MT);   // (64, 8): x=split -> XCD=split%8
  fused_gemm_partial<<<g1, 512, 0, stream>>>(pbf, qbf0, wbf, maskp, label, ws);
  finalize_rows<<<B_, 128, 0, stream>>>(p, queue, maskp, label, ws, out);
  reduce_final<<<1, 256, 0, stream>>>(label, ws, out);
}

// Round 5
// 550.083 us; speedup vs baseline: 1.1257x; 1.1257x over previous
//
#include <hip/hip_runtime.h>
#include <stdint.h>

#define B_ 1024
#define Q_ 65536
#define D_ 512
#define MT 128
#define NT 128
#define BK 64
#define NSPLIT 64
#define NCHUNK (Q_ / NSPLIT)   // 1024
#define NTILES (NCHUNK / NT)   // 8
#define KITERS (D_ / BK)       // 8

#define SCALE32 32.0f
#define C32 46.16624130844683f   // 32 * log2(e)

// ---- workspace layout (bytes) ----
// [0,8K)   : rowv[2][B] f32 per-row loss values
// [16K)    : LSE partials float2(Z_mat0, Z_mat1), idx row*64+split  (512 KB)
// [1 MB)   : top-10 partials, idx ((mat*B+row)*64+split)*10         (5.24 MB)
// [8 MB)   : p bf16 (1 MB)
// [12 MB)  : queue[0] bf16 (64 MB)
// [76 MB)  : w = m*q1+(1-m)*q0 bf16, written only where mask!=0 (64 MB region)
#define WS_ROWV 0
#define WS_LSE  16384
#define WS_TOPK (1u * 1024u * 1024u)
#define WS_PBF  (8u * 1024u * 1024u)
#define WS_QBF0 (12u * 1024u * 1024u)
#define WS_WBF  (76u * 1024u * 1024u)

// ---- LDS: staging sA[0,16K) sB0[16K,32K) sB1[32K,48K); 16B-XOR swizzle
// (round-0 exact geometry: 40 MB FETCH, 2.9M conflicts verified).
// topk compact (16 KB) aliases sA between K-loop and next nt staging.
#define SA_OFF 0
#define SB0_OFF 16384
#define SB1_OFF 32768

typedef __attribute__((ext_vector_type(8))) short short8;
typedef __attribute__((ext_vector_type(4))) short short4v;
typedef __attribute__((ext_vector_type(4))) float f32x4;

__device__ __forceinline__ unsigned short f2bf(float x) {
  union { float f; uint32_t u; } v; v.f = x;
  uint32_t r = v.u + 0x7fffu + ((v.u >> 16) & 1u);   // RNE
  return (unsigned short)(r >> 16);
}

__device__ __forceinline__ float bf2f(short u) {
  union { uint32_t i; float f; } v;
  v.i = ((uint32_t)(unsigned short)u) << 16;
  return v.f;
}

__device__ __forceinline__ void async16(void* lds, const void* g) {
  void* gg = (void*)g;
  __builtin_amdgcn_global_load_lds(
      (__attribute__((address_space(1))) unsigned int*)gg,
      (__attribute__((address_space(3))) unsigned int*)lds,
      16, 0, 0);
}

__device__ __forceinline__ void tkins(float v,
    float& t0, float& t1, float& t2, float& t3, float& t4,
    float& t5, float& t6, float& t7, float& t8, float& t9) {
  if (v > t9) {
    t9 = (v > t8) ? t8 : v;
    t8 = (v > t8) ? ((v > t7) ? t7 : v) : t8;
    t7 = (v > t7) ? ((v > t6) ? t6 : v) : t7;
    t6 = (v > t6) ? ((v > t5) ? t5 : v) : t6;
    t5 = (v > t5) ? ((v > t4) ? t4 : v) : t5;
    t4 = (v > t4) ? ((v > t3) ? t3 : v) : t4;
    t3 = (v > t3) ? ((v > t2) ? t2 : v) : t3;
    t2 = (v > t2) ? ((v > t1) ? t1 : v) : t2;
    t1 = (v > t1) ? ((v > t0) ? t0 : v) : t1;
    t0 = (v > t0) ? v : t0;
  }
}

#define TKA(v, a) tkins((v), a[0], a[1], a[2], a[3], a[4], a[5], a[6], a[7], a[8], a[9])

// fused converter: queue fp32 -> qbf0 always; wbf only where mask!=0; p -> pbf
__global__ void cvt_all(const float* __restrict__ q, const float* __restrict__ p,
                        const float* __restrict__ mask,
                        unsigned short* __restrict__ qbf0,
                        unsigned short* __restrict__ wbf,
                        unsigned short* __restrict__ pbf) {
  const int wv = threadIdx.x >> 6;
  const int lane = threadIdx.x & 63;
  const int b = blockIdx.x;
  if (b < Q_ / 4) {
    const int row = b * 4 + wv;
    const float* q0r = q + (size_t)row * D_ + lane * 8;
    float4 a = ((const float4*)q0r)[0];
    float4 bb = ((const float4*)q0r)[1];
    short8 o;
    o[0] = (short)f2bf(a.x); o[1] = (short)f2bf(a.y);
    o[2] = (short)f2bf(a.z); o[3] = (short)f2bf(a.w);
    o[4] = (short)f2bf(bb.x); o[5] = (short)f2bf(bb.y);
    o[6] = (short)f2bf(bb.z); o[7] = (short)f2bf(bb.w);
    *(short8*)(qbf0 + (size_t)row * D_ + lane * 8) = o;
    float m = mask[row];
    if (m != 0.0f) {      // wave-uniform; ~10% of rows
      const float* q1r = q0r + (size_t)Q_ * D_;
      float4 c = ((const float4*)q1r)[0];
      float4 d = ((const float4*)q1r)[1];
      a.x = fmaf(m, c.x - a.x, a.x); a.y = fmaf(m, c.y - a.y, a.y);
      a.z = fmaf(m, c.z - a.z, a.z); a.w = fmaf(m, c.w - a.w, a.w);
      bb.x = fmaf(m, d.x - bb.x, bb.x); bb.y = fmaf(m, d.y - bb.y, bb.y);
      bb.z = fmaf(m, d.z - bb.z, bb.z); bb.w = fmaf(m, d.w - bb.w, bb.w);
      o[0] = (short)f2bf(a.x); o[1] = (short)f2bf(a.y);
      o[2] = (short)f2bf(a.z); o[3] = (short)f2bf(a.w);
      o[4] = (short)f2bf(bb.x); o[5] = (short)f2bf(bb.y);
      o[6] = (short)f2bf(bb.z); o[7] = (short)f2bf(bb.w);
      *(short8*)(wbf + (size_t)row * D_ + lane * 8) = o;
    }
  } else {
    const int row = (b - Q_ / 4) * 4 + wv;
    const float* pr = p + (size_t)row * D_ + lane * 8;
    float4 a = ((const float4*)pr)[0];
    float4 bb = ((const float4*)pr)[1];
    short8 o;
    o[0] = (short)f2bf(a.x); o[1] = (short)f2bf(a.y);
    o[2] = (short)f2bf(a.z); o[3] = (short)f2bf(a.w);
    o[4] = (short)f2bf(bb.x); o[5] = (short)f2bf(bb.y);
    o[6] = (short)f2bf(bb.z); o[7] = (short)f2bf(bb.w);
    *(short8*)(pbf + (size_t)row * D_ + lane * 8) = o;
  }
}

// grid (64, 8): x=split -> XCD=split%8, all 512 blocks co-resident (2/CU).
// Round-0 geometry exact (256 thr, 4 waves 2x2, BK=64, 53KB LDS). One change:
// staging issue reordered {A,B0}x4 then {B1}x4, and the drain is split:
// vmcnt(4)+barrier -> acc0 compute -> vmcnt(0)+barrier -> acc1 compute, so
// B1's latency hides under acc0's MFMAs. A-fragments persist in regs (af[2][4]).
__global__ __launch_bounds__(256, 2) void fused_gemm_partial(
    const unsigned short* __restrict__ pbf,
    const unsigned short* __restrict__ qbf0,
    const unsigned short* __restrict__ wbf,
    const float* __restrict__ maskp,
    const int* __restrict__ label,
    char* __restrict__ ws) {
  __shared__ __align__(16) unsigned char smem[49152];
  __shared__ float maskb[NT];
  __shared__ float zacc[MT][4];      // [row][wc*2+mat], accumulated across nt
  __shared__ int olist[MT];
  __shared__ int rowmap[MT];
  __shared__ int sh_ocount;

  const int tid = threadIdx.x;
  const int split = blockIdx.x;       // 0..63
  const int mblk = blockIdx.y;        // 0..7
  const int lane = tid & 63;
  const int wv = tid >> 6;
  const int wr = wv >> 1;
  const int wc = wv & 1;
  const int lr = lane & 15;
  const int lg = lane >> 4;

  if (tid == 0) sh_ocount = 0;
  if (tid < MT) {
    rowmap[tid] = -1;
    zacc[tid][0] = 0.0f; zacc[tid][1] = 0.0f;
    zacc[tid][2] = 0.0f; zacc[tid][3] = 0.0f;
  }
  __syncthreads();
  if (tid < MT) {
    if (label[mblk * MT + tid] == -1) {
      int k = atomicAdd(&sh_ocount, 1);
      olist[k] = tid;
    }
  }
  __syncthreads();
  const int noc = sh_ocount;
  if (tid < noc) rowmap[olist[tid]] = tid;
  __syncthreads();
  const int nchunks = (noc + 31) >> 5;

  // staging lane constants: lane covers row slot*8+(lane>>3),
  // swizzled col16 = (lane&7) ^ (row&7)
  const int srow = lane >> 3;
  const int sc16 = (lane & 7) ^ srow;
  const size_t g_lane_off = (size_t)srow * D_ + sc16 * 8;

  // owner top-10 (only threads with tid&3==0 and pair<64 use it)
  float T[10];
#pragma unroll
  for (int i = 0; i < 10; ++i) T[i] = -1e30f;

  for (int nt = 0; nt < NTILES; ++nt) {
    const int nbase = split * NCHUNK + nt * NT;
    if (tid < NT) maskb[tid] = maskp[nbase + tid];
    __syncthreads();   // maskb ready; also fences smem reuse from prev nt scan

    // per-slot B1 source select (mask==0 rows read qbf0 -> L2-hot after B0)
    const unsigned short* b1b[4];
#pragma unroll
    for (int t = 0; t < 4; ++t) {
      const int rowl = (wv * 4 + t) * 8 + srow;
      b1b[t] = (maskb[rowl] != 0.0f) ? wbf : qbf0;
    }

    f32x4 acc0[4][4], acc1[4][4];
#pragma unroll
    for (int i = 0; i < 4; ++i)
#pragma unroll
      for (int j = 0; j < 4; ++j) {
        f32x4 z = {0.0f, 0.0f, 0.0f, 0.0f};
        acc0[i][j] = z;
        acc1[i][j] = z;
      }

    for (int kk = 0; kk < KITERS; ++kk) {
      const size_t kcol = (size_t)kk * BK;
      // issue order: 8x {A,B0} first, then 4x {B1} (same addrs as round-0)
#pragma unroll
      for (int t = 0; t < 4; ++t) {
        const int slot = wv * 4 + t;
        const size_t rbase = (size_t)slot * 8;
        async16(smem + SA_OFF + slot * 1024,
                pbf + ((size_t)mblk * MT + rbase) * D_ + kcol + g_lane_off);
        async16(smem + SB0_OFF + slot * 1024,
                qbf0 + ((size_t)nbase + rbase) * D_ + kcol + g_lane_off);
      }
#pragma unroll
      for (int t = 0; t < 4; ++t) {
        const int slot = wv * 4 + t;
        const size_t rbase = (size_t)slot * 8;
        async16(smem + SB1_OFF + slot * 1024,
                b1b[t] + ((size_t)nbase + rbase) * D_ + kcol + g_lane_off);
      }

      // phase A: wait own A+B0 (8 oldest of 12) -> barrier -> acc0 compute
      asm volatile("s_waitcnt vmcnt(4)" ::: "memory");
      __builtin_amdgcn_s_barrier();

      short8 af[2][4];
#pragma unroll
      for (int s = 0; s < 2; ++s) {
        const int xs = ((s * 4 + lg) ^ (lr & 7)) * 16;
        short8 bfr[4];
#pragma unroll
        for (int i = 0; i < 4; ++i)
          af[s][i] = *(const short8*)(smem + SA_OFF + (wr * 64 + i * 16 + lr) * 128 + xs);
#pragma unroll
        for (int j = 0; j < 4; ++j)
          bfr[j] = *(const short8*)(smem + SB0_OFF + (wc * 64 + j * 16 + lr) * 128 + xs);
#pragma unroll
        for (int i = 0; i < 4; ++i)
#pragma unroll
          for (int j = 0; j < 4; ++j)
            acc0[i][j] = __builtin_amdgcn_mfma_f32_16x16x32_bf16(af[s][i], bfr[j], acc0[i][j], 0, 0, 0);
      }

      // phase B: wait own B1 -> barrier -> acc1 compute (af reused from regs)
      asm volatile("s_waitcnt vmcnt(0)" ::: "memory");
      __builtin_amdgcn_s_barrier();

#pragma unroll
      for (int s = 0; s < 2; ++s) {
        const int xs = ((s * 4 + lg) ^ (lr & 7)) * 16;
        short8 bfr[4];
#pragma unroll
        for (int j = 0; j < 4; ++j)
          bfr[j] = *(const short8*)(smem + SB1_OFF + (wc * 64 + j * 16 + lr) * 128 + xs);
#pragma unroll
        for (int i = 0; i < 4; ++i)
#pragma unroll
          for (int j = 0; j < 4; ++j)
            acc1[i][j] = __builtin_amdgcn_mfma_f32_16x16x32_bf16(af[s][i], bfr[j], acc1[i][j], 0, 0, 0);
      }
      __syncthreads();   // LDS safe to overwrite by next kk's stage
    }

    // ---- Z epilogue: exps in regs, lr-shuffle reduce, LDS accumulate ----
#pragma unroll
    for (int i = 0; i < 4; ++i)
#pragma unroll
      for (int k = 0; k < 4; ++k) {
        float a0 = 0.0f, a1 = 0.0f;
#pragma unroll
        for (int j = 0; j < 4; ++j) {
          a0 += __builtin_amdgcn_exp2f(fmaf(acc0[i][j][k], C32, -C32));
          a1 += __builtin_amdgcn_exp2f(fmaf(acc1[i][j][k], C32, -C32));
        }
#pragma unroll
        for (int m = 1; m < 16; m <<= 1) {
          a0 += __shfl_xor(a0, m, 64);
          a1 += __shfl_xor(a1, m, 64);
        }
        if (lr == 0) {
          const int r = wr * 64 + i * 16 + lg * 4 + k;
          zacc[r][wc * 2 + 0] += a0;
          zacc[r][wc * 2 + 1] += a1;
        }
      }

    // ---- top-10 for outlier rows: LDS compact -> 4-thread scans -> merge ----
    for (int c = 0; c < nchunks; ++c) {
      unsigned short* cp = (unsigned short*)smem;   // aliases sA (16 KB)
#pragma unroll
      for (int i = 0; i < 4; ++i)
#pragma unroll
        for (int k = 0; k < 4; ++k) {
          const int r = wr * 64 + i * 16 + lg * 4 + k;
          const int o = rowmap[r];
          const int ol = o - c * 32;
          if (o >= 0 && ol >= 0 && ol < 32) {
#pragma unroll
            for (int j = 0; j < 4; ++j) {
              const int col = wc * 64 + j * 16 + lr;
              cp[ol * 128 + col] = f2bf(acc0[i][j][k]);
              cp[(32 + ol) * 128 + col] = f2bf(acc1[i][j][k]);
            }
          }
        }
      __syncthreads();

      {
        float tl[10];
#pragma unroll
        for (int r = 0; r < 10; ++r) tl[r] = -1e30f;
        const int pair = tid >> 2;      // 0..63: (orow, mat)
        const int q4 = tid & 3;
        const int orow = pair >> 1, mat = pair & 1;
        const int o = c * 32 + orow;
        if (o < noc) {
          const unsigned short* rp = cp + (mat * 32 + orow) * 128 + q4 * 32;
#pragma unroll
          for (int cc = 0; cc < 8; ++cc) {
            short4v v = *(const short4v*)(rp + cc * 4);
            TKA(bf2f(v.x), tl); TKA(bf2f(v.y), tl);
            TKA(bf2f(v.z), tl); TKA(bf2f(v.w), tl);
          }
          // merge across the 4 quarter-threads (same wave: xor 1 then 2)
          float ot[10];
#pragma unroll
          for (int r = 0; r < 10; ++r) ot[r] = __shfl_xor(tl[r], 1, 64);
#pragma unroll
          for (int r = 0; r < 10; ++r) TKA(ot[r], tl);
#pragma unroll
          for (int r = 0; r < 10; ++r) ot[r] = __shfl_xor(tl[r], 2, 64);
#pragma unroll
          for (int r = 0; r < 10; ++r) TKA(ot[r], tl);
          if (q4 == 0) {
            if (c == 0) {
#pragma unroll
              for (int r = 0; r < 10; ++r) TKA(tl[r], T);
            } else {
              // rare overflow path (noc > 32): RMW ws slot per nt
              float* slot = (float*)(ws + WS_TOPK) +
                  ((size_t)(mat * B_ + mblk * MT + olist[o]) * NSPLIT + split) * 10;
              if (nt == 0) {
#pragma unroll
                for (int r = 0; r < 10; ++r) slot[r] = tl[r];
              } else {
                float cur[10];
#pragma unroll
                for (int r = 0; r < 10; ++r) cur[r] = slot[r];
#pragma unroll
                for (int r = 0; r < 10; ++r) TKA(tl[r], cur);
#pragma unroll
                for (int r = 0; r < 10; ++r) slot[r] = cur[r];
              }
            }
          }
        }
      }
      __syncthreads();
    }
  }

  // ---- block end: write Z partials and owner top-10 lists ----
  if (tid < MT) {
    float2* lseo = (float2*)(ws + WS_LSE);
    lseo[(size_t)(mblk * MT + tid) * NSPLIT + split] =
        make_float2(zacc[tid][0] + zacc[tid][2], zacc[tid][1] + zacc[tid][3]);
  }
  {
    const int pair = tid >> 2;
    const int q4 = tid & 3;
    const int orow = pair >> 1, mat = pair & 1;
    if (q4 == 0 && orow < noc && orow < 32) {
      float* slot = (float*)(ws + WS_TOPK) +
          ((size_t)(mat * B_ + mblk * MT + olist[orow]) * NSPLIT + split) * 10;
#pragma unroll
      for (int r = 0; r < 10; ++r) slot[r] = T[r];
    }
  }
}

// per-row: no global atomics — each row writes rowv[l*B+row]; reduce_final sums.
__global__ void finalize_rows(
    const float* __restrict__ p, const float* __restrict__ queue,
    const float* __restrict__ maskp, const int* __restrict__ label,
    char* __restrict__ ws, float* __restrict__ out) {
  const int row = blockIdx.x;
  const int l = threadIdx.x >> 6;     // 0: cos1 loss, 1: cos2 loss
  const int lane = threadIdx.x & 63;
  const int lab = label[row];
  float* rowv = (float*)(ws + WS_ROWV);

  if (lab != -1) {
    // ---- sum 64 split Z partials ----
    const float2* lsep = (const float2*)(ws + WS_LSE) + (size_t)row * NSPLIT;
    float2 zz = lsep[lane];
    float z = (l == 0) ? zz.x : zz.y;
#pragma unroll
    for (int o = 1; o < 64; o <<= 1) z += __shfl_xor(z, o, 64);

    // ---- exact fp32 gt dot(s) ----
    const float* prow = p + (size_t)row * D_;
    const float* q0r = queue + (size_t)lab * D_;
    const float* q1r = queue + ((size_t)Q_ + (size_t)lab) * D_;
    int c = lane * 8;
    float4 a0 = *(const float4*)(prow + c);
    float4 a1 = *(const float4*)(prow + c + 4);
    float4 b0 = *(const float4*)(q0r + c);
    float4 b1 = *(const float4*)(q0r + c + 4);
    float d0 = a0.x * b0.x + a0.y * b0.y + a0.z * b0.z + a0.w * b0.w
             + a1.x * b1.x + a1.y * b1.y + a1.z * b1.z + a1.w * b1.w;
    float d1 = 0.0f;
    if (l == 1) {
      float4 c0 = *(const float4*)(q1r + c);
      float4 c1 = *(const float4*)(q1r + c + 4);
      d1 = a0.x * c0.x + a0.y * c0.y + a0.z * c0.z + a0.w * c0.w
         + a1.x * c1.x + a1.y * c1.y + a1.z * c1.z + a1.w * c1.w;
    }
#pragma unroll
    for (int o = 1; o < 64; o <<= 1) {
      d0 += __shfl_xor(d0, o, 64);
      d1 += __shfl_xor(d1, o, 64);
    }
    float gt;
    if (l == 0) gt = d0;
    else { float m = maskp[lab]; gt = fmaf(m, d1 - d0, d0); }

    if (lane == 0) {
      float e1 = __builtin_amdgcn_exp2f(fmaf(gt, C32, -C32));
      float e2 = __builtin_amdgcn_exp2f(fmaf(gt - 0.4f, C32, -C32));
      float Zc = z - e1 + e2;
      float ce = 32.0f + __logf(Zc) - (gt - 0.4f) * SCALE32;
      rowv[l * B_ + row] = ce;
    }
  } else {
    // ---- merge 64 sorted top-10 lists: 10-round wave tournament ----
    const float* tp = (const float*)(ws + WS_TOPK) +
                      ((size_t)l * B_ + row) * NSPLIT * 10 + (size_t)lane * 10;
    float t0 = tp[0], t1 = tp[1], t2 = tp[2], t3 = tp[3], t4 = tp[4];
    float t5 = tp[5], t6 = tp[6], t7 = tp[7], t8 = tp[8], t9 = tp[9];
    float ssum = 0.0f;
#pragma unroll
    for (int r10 = 0; r10 < 10; ++r10) {
      float v = t0;
      int idx = lane;
#pragma unroll
      for (int o = 1; o < 64; o <<= 1) {
        float ov = __shfl_xor(v, o, 64);
        int oi = __shfl_xor(idx, o, 64);
        bool take = (ov > v) || (ov == v && oi < idx);
        v = take ? ov : v;
        idx = take ? oi : idx;
      }
      ssum += fmaxf(v, 0.0f);
      if (idx == lane) {
        t0 = t1; t1 = t2; t2 = t3; t3 = t4; t4 = t5;
        t5 = t6; t6 = t7; t7 = t8; t8 = t9; t9 = -1e30f;
      }
    }
    if (lane == 0) rowv[l * B_ + row] = ssum * 0.1f;
  }
}

// single-block deterministic reduction (no contended atomics)
__global__ void reduce_final(const int* __restrict__ label,
                             const char* __restrict__ ws,
                             float* __restrict__ out) {
  __shared__ float sce[4], sng[4];
  __shared__ int snp[4], snn[4];
  const int tid = threadIdx.x;        // 256 threads
  const float* rowv = (const float*)(ws + WS_ROWV);
  float ce = 0.0f, ng = 0.0f;
  int np = 0, nn = 0;
  for (int r = tid; r < B_; r += 256) {
    float v = rowv[r] + rowv[B_ + r];
    if (label[r] != -1) { ce += v; ++np; }
    else { ng += v; ++nn; }
  }
#pragma unroll
  for (int o = 1; o < 64; o <<= 1) {
    ce += __shfl_xor(ce, o, 64);
    ng += __shfl_xor(ng, o, 64);
    np += __shfl_xor(np, o, 64);
    nn += __shfl_xor(nn, o, 64);
  }
  const int wv = tid >> 6, lane = tid & 63;
  if (lane == 0) { sce[wv] = ce; sng[wv] = ng; snp[wv] = np; snn[wv] = nn; }
  __syncthreads();
  if (tid == 0) {
    float c = 0.0f, g = 0.0f; int p = 0, n = 0;
#pragma unroll
    for (int i = 0; i < 4; ++i) { c += sce[i]; g += sng[i]; p += snp[i]; n += snn[i]; }
    float loss = 0.0f;
    if (p > 0) loss += c / (float)p;
    if (n > 0) loss += g / (float)n;
    out[0] = loss;
  }
}

extern "C" void kernel_launch(void* const* d_in, const int* in_sizes, int n_in,
                              void* d_out, int out_size, void* d_ws, size_t ws_size,
                              hipStream_t stream) {
  const float* p     = (const float*)d_in[0];
  const float* queue = (const float*)d_in[1];
  const float* maskp = (const float*)d_in[2];
  const int*   label = (const int*)d_in[3];
  float* out = (float*)d_out;
  char* ws = (char*)d_ws;

  unsigned short* pbf  = (unsigned short*)(ws + WS_PBF);
  unsigned short* qbf0 = (unsigned short*)(ws + WS_QBF0);
  unsigned short* wbf  = (unsigned short*)(ws + WS_WBF);

  cvt_all<<<Q_ / 4 + B_ / 4, 256, 0, stream>>>(queue, p, maskp, qbf0, wbf, pbf);

  dim3 g1(NSPLIT, B_ / MT);   // (64, 8): x=split -> XCD=split%8
  fused_gemm_partial<<<g1, 256, 0, stream>>>(pbf, qbf0, wbf, maskp, label, ws);
  finalize_rows<<<B_, 128, 0, stream>>>(p, queue, maskp, label, ws, out);
  reduce_final<<<1, 256, 0, stream>>>(label, ws, out);
}